// Round 15
// baseline (36.548 us; speedup 1.0000x reference)
//
#include <hip/hip_runtime.h>
#include <hip/hip_bf16.h>

#define B 16
#define N 10000
#define D 64
#define R 64
#define H 512
#define K 32
#define NRBF 79                      // ceil(10000 / 128) rbf blocks per b
#define NBUCK 4096

typedef unsigned long long ull;
typedef short s16x8 __attribute__((ext_vector_type(8)));
typedef float f32x16 __attribute__((ext_vector_type(16)));

// ---------- ws layout (bytes) ----------
// ow   : B*K f32      @ 0        (2048)
// nm2  : B*K f32      @ 2048     (2048)   -0.5*||mean||^2
// tmh  : B*K*D bf16   @ 4096     (65536)  mean hi
// tml  : B*K*D bf16   @ 69632    (65536)  mean lo
// part : B*NRBF f32   @ 135168   (5056)

static __device__ __forceinline__ ushort f2bf_bits(float x) {
    __hip_bfloat16 h = __float2bfloat16(x);
    return *reinterpret_cast<ushort*>(&h);
}
static __device__ __forceinline__ float bf_hi_f(float x) {
    return __bfloat162float(__float2bfloat16(x));
}
// split 8 floats (two float4) into bf16 hi / lo fragments
static __device__ __forceinline__ void split8(const float4 a, const float4 b,
                                              s16x8& hi, s16x8& lo) {
    const float v[8] = {a.x, a.y, a.z, a.w, b.x, b.y, b.z, b.w};
    #pragma unroll
    for (int i = 0; i < 8; ++i) {
        const ushort h = f2bf_bits(v[i]);
        const float hf = __uint_as_float(((unsigned)h) << 16);
        hi[i] = (short)h;
        lo[i] = (short)f2bf_bits(v[i] - hf);
    }
}

// ------- kernel 1: redundant top-K select + MLP (16 blocks per b) -------
// Every block of batch b recomputes the SAME exact top-K via histogram select
// (deterministic: same input -> same histogram -> same threshold; slots are
// value-determined ranks with key = val_bits<<32 | ~idx, preserving jax's
// smaller-index tie-break). Selection runs at 256 blocks (8 waves/CU) instead
// of a separate 16-block latency-bound dispatch; oidx never leaves LDS.
// Two-pass scan keeps VGPRs low: pass 1 histograms, pass 2 re-reads e
// (L2-hot) and collects candidates >= threshold. Then the existing MLP for
// this block's 2 selected rows; rp computed inline (W1 cols 0..R).
__global__ __launch_bounds__(512) void k_sel_mlp(
        const float* __restrict__ e, const float* __restrict__ rE,
        const float* __restrict__ sup, const float* __restrict__ W1,
        const float* __restrict__ b1, const float* __restrict__ W2,
        const float* __restrict__ b2,
        float* __restrict__ ow, ushort* __restrict__ tmh,
        ushort* __restrict__ tml, float* __restrict__ nm2) {
    const int b = blockIdx.x >> 4, pr = blockIdx.x & 15;
    const int tid = threadIdx.x;
    __shared__ unsigned hist[NBUCK];
    __shared__ ull cand[1024];
    __shared__ float rEs[R];
    __shared__ int oidxS[K];
    __shared__ float sA[D], sB[D];
    __shared__ float hA[H], hB[H];
    __shared__ float partA[512], partB[512];
    __shared__ unsigned cnt;
    __shared__ int tsh;

    #pragma unroll
    for (int i = 0; i < NBUCK / 512; ++i) hist[tid + i * 512] = 0;
    if (tid == 0) cnt = 0;
    if (tid < R) rEs[tid] = rE[b * R + tid];
    __syncthreads();

    // ---- pass 1: histogram (2500 float4 = 10000 elems; 5 vec-loads/thread)
    const float4* e4 = (const float4*)(e + b * N);
    #pragma unroll
    for (int i = 0; i < 5; ++i) {
        const int fi = tid + i * 512;
        if (fi < 2500) {
            const float4 v4 = e4[fi];
            const float vv[4] = {v4.x, v4.y, v4.z, v4.w};
            #pragma unroll
            for (int j = 0; j < 4; ++j) {
                int bu = (int)(vv[j] * (float)NBUCK);
                bu = bu > NBUCK - 1 ? NBUCK - 1 : (bu < 0 ? 0 : bu);
                atomicAdd(&hist[bu], 1u);
            }
        }
    }
    __syncthreads();

    // wave 0: parallel suffix scan from the top, 64 buckets per step
    if (tid < 64) {
        unsigned acc = 0;
        for (int w = 0; w < NBUCK / 64; ++w) {
            const int j = NBUCK - 1 - (w * 64 + tid);
            unsigned p = hist[j];
            #pragma unroll
            for (int off = 1; off < 64; off <<= 1) {
                unsigned o = __shfl_up(p, off, 64);
                if (tid >= off) p += o;
            }
            const ull mask = __ballot(acc + p >= K);
            if (mask) {
                if (tid == 0) {
                    const int l0 = __ffsll((long long)mask) - 1;
                    tsh = NBUCK - 1 - (w * 64 + l0);
                }
                break;
            }
            acc += (unsigned)__shfl((int)p, 63, 64);
        }
    }
    __syncthreads();
    const int t = tsh;

    // ---- pass 2: re-read (L2-hot), collect candidates >= threshold
    #pragma unroll
    for (int i = 0; i < 5; ++i) {
        const int fi = tid + i * 512;
        if (fi < 2500) {
            const float4 v4 = e4[fi];
            const float vv[4] = {v4.x, v4.y, v4.z, v4.w};
            #pragma unroll
            for (int j = 0; j < 4; ++j) {
                int bu = (int)(vv[j] * (float)NBUCK);
                bu = bu > NBUCK - 1 ? NBUCK - 1 : (bu < 0 ? 0 : bu);
                if (bu >= t) {
                    const unsigned p = atomicAdd(&cnt, 1u);
                    if (p < 1024u)
                        cand[p] = ((ull)__float_as_uint(vv[j]) << 32) |
                                  (unsigned)(0xFFFFFFFFu - (unsigned)(fi * 4 + j));
                }
            }
        }
    }
    __syncthreads();

    const unsigned C = cnt < 1024u ? cnt : 1024u;
    for (unsigned i = tid; i < C; i += 512) {
        const ull mine = cand[i];
        int rank = 0;
        for (unsigned j = 0; j < C; ++j) rank += (cand[j] > mine);
        if (rank < K) {
            oidxS[rank] = (int)(0xFFFFFFFFu - (unsigned)(mine & 0xFFFFFFFFu));
            if (pr == 0)                      // one block per b writes globals
                ow[b * K + rank] = __uint_as_float((unsigned)(mine >> 32));
        }
    }
    __syncthreads();

    // ---- MLP on this block's 2 selected rows ----
    const int gk = b * K + pr * 2;
    const int id0 = oidxS[pr * 2], id1 = oidxS[pr * 2 + 1];
    if (tid < D) sA[tid] = sup[id0 * D + tid];
    else if (tid < 2 * D) sB[tid - D] = sup[id1 * D + (tid - D)];
    __syncthreads();

    {   // phase 1: one h-row per thread; rp inline (W1 cols 0..R, same row)
        const float4* w = (const float4*)(W1 + tid * (R + D));
        float rpv = b1[tid];
        #pragma unroll
        for (int i = 0; i < R / 4; ++i) {
            const float4 wv = w[i];
            rpv += wv.x * rEs[4 * i] + wv.y * rEs[4 * i + 1] +
                   wv.z * rEs[4 * i + 2] + wv.w * rEs[4 * i + 3];
        }
        float a0 = rpv, a1 = rpv;
        #pragma unroll
        for (int i = 0; i < D / 4; ++i) {
            const float4 wv = w[R / 4 + i];
            a0 += wv.x * sA[4 * i] + wv.y * sA[4 * i + 1] +
                  wv.z * sA[4 * i + 2] + wv.w * sA[4 * i + 3];
            a1 += wv.x * sB[4 * i] + wv.y * sB[4 * i + 1] +
                  wv.z * sB[4 * i + 2] + wv.w * sB[4 * i + 3];
        }
        hA[tid] = fmaxf(a0, 0.f);
        hB[tid] = fmaxf(a1, 0.f);
    }
    __syncthreads();

    {   // phase 2: d = tid&63, 8 chunks of 64 over H
        const int d = tid & 63, ch = tid >> 6;
        const float4* w2 = (const float4*)(W2 + d * H + ch * 64);
        float a0 = 0.f, a1 = 0.f;
        #pragma unroll
        for (int i = 0; i < 16; ++i) {
            const float4 wv = w2[i];
            const int hb = ch * 64 + 4 * i;
            a0 += wv.x * hA[hb] + wv.y * hA[hb + 1] + wv.z * hA[hb + 2] + wv.w * hA[hb + 3];
            a1 += wv.x * hB[hb] + wv.y * hB[hb + 1] + wv.z * hB[hb + 2] + wv.w * hB[hb + 3];
        }
        partA[tid] = a0;
        partB[tid] = a1;
    }
    __syncthreads();

    if (tid < 128) {            // wave 0 -> pair 0, wave 1 -> pair 1
        const int d = tid & 63, w = tid >> 6;
        const float* part = w == 0 ? partA : partB;
        float m = b2[d];
        #pragma unroll
        for (int c = 0; c < 8; ++c) m += part[c * 64 + d];
        const float hf = bf_hi_f(m);
        tmh[(gk + w) * D + d] = f2bf_bits(m);
        tml[(gk + w) * D + d] = f2bf_bits(m - hf);
        float sq = m * m;
        #pragma unroll
        for (int off = 32; off > 0; off >>= 1) sq += __shfl_down(sq, off, 64);
        if (d == 0) nm2[gk + w] = -0.5f * sq;
    }
}

// ---------------- kernel 2: RBF via 32x32x16 split-bf16 MFMA ----------------
// block = 4 waves x 32 rows = 128 rows, one b. Per wave: C[32n x 32k] via
// 4 k-steps x 3 split products = 12 mfma_f32_32x32x16_bf16 (acc f32x16).
// A: row=lane&31, d = s*16 + (lane>>5)*8 + j (f32 load + in-reg bf16 split).
// B: col(k)=lane&31, same d map. C/D: col=lane&31, row=(r&3)+8*(r>>2)+4*(lane>>5).
// Epilogue: exp, then pairwise tree rowsum -> S_r at lane r32&15==r; one
// coalesced store per half.
__global__ __launch_bounds__(256) void k_rbf(
        const float* __restrict__ sup,
        const ushort* __restrict__ tmh, const ushort* __restrict__ tml,
        const float* __restrict__ nm2, const float* __restrict__ ow,
        float* __restrict__ out, float* __restrict__ part) {
    const int b = blockIdx.y;
    const int tid = threadIdx.x;
    const int lane = tid & 63;
    const int wt = tid >> 6;
    const int g = lane >> 5;                 // d-offset group / row half
    const int r32 = lane & 31;
    const int nb = blockIdx.x * 128 + wt * 32;
    __shared__ float wred[4];

    const int arow = nb + r32;
    const int arowc = arow < N ? arow : N - 1;

    // A: load f32 row chunks, split to bf16 hi/lo in-register
    s16x8 ah[4], al[4];
    float s2o = 0.f;
    const float4* sp = (const float4*)(sup + arowc * D);
    #pragma unroll
    for (int s = 0; s < 4; ++s) {
        const float4 u0 = sp[s * 4 + g * 2];
        const float4 u1 = sp[s * 4 + g * 2 + 1];
        s2o += u0.x * u0.x + u0.y * u0.y + u0.z * u0.z + u0.w * u0.w
             + u1.x * u1.x + u1.y * u1.y + u1.z * u1.z + u1.w * u1.w;
        split8(u0, u1, ah[s], al[s]);
    }
    const float ns2 = -0.5f * (s2o + __shfl_xor(s2o, 32, 64)); // row r32 norm

    // B: bf16 hi/lo fragments of tm row k = r32
    const ushort* ph = tmh + (b * K + r32) * D;
    const ushort* pl = tml + (b * K + r32) * D;
    s16x8 bh[4], bl[4];
    #pragma unroll
    for (int s = 0; s < 4; ++s) {
        bh[s] = *(const s16x8*)(ph + s * 16 + g * 8);
        bl[s] = *(const s16x8*)(pl + s * 16 + g * 8);
    }

    f32x16 acc = {0.f, 0.f, 0.f, 0.f, 0.f, 0.f, 0.f, 0.f,
                  0.f, 0.f, 0.f, 0.f, 0.f, 0.f, 0.f, 0.f};
    #pragma unroll
    for (int s = 0; s < 4; ++s) {            // hi*hi + hi*lo + lo*hi
        acc = __builtin_amdgcn_mfma_f32_32x32x16_bf16(ah[s], bh[s], acc, 0, 0, 0);
        acc = __builtin_amdgcn_mfma_f32_32x32x16_bf16(ah[s], bl[s], acc, 0, 0, 0);
        acc = __builtin_amdgcn_mfma_f32_32x32x16_bf16(al[s], bh[s], acc, 0, 0, 0);
    }

    const float wk = ow[b * K + r32];
    const float qk = nm2[b * K + r32];

    float val[16];
    #pragma unroll
    for (int r = 0; r < 16; ++r) {
        const int rowr = (r & 3) + 8 * (r >> 2) + 4 * g;
        const float nsr = __shfl(ns2, rowr, 64);   // ns2 lives at lane rowr
        val[r] = (nb + rowr) < N ? wk * __expf(nsr + qk + acc[r]) : 0.f;
    }

    // ---- pairwise tree rowsum over the 32 cols ----
    #pragma unroll
    for (int r = 0; r < 16; ++r) val[r] += __shfl_xor(val[r], 16, 64);
    float v8[8];
    #pragma unroll
    for (int i = 0; i < 8; ++i) {
        float t = (r32 & 1) ? val[2 * i] : val[2 * i + 1];
        t = __shfl_xor(t, 1, 64);
        v8[i] = ((r32 & 1) ? val[2 * i + 1] : val[2 * i]) + t;
    }
    float v4[4];
    #pragma unroll
    for (int i = 0; i < 4; ++i) {
        float t = (r32 & 2) ? v8[2 * i] : v8[2 * i + 1];
        t = __shfl_xor(t, 2, 64);
        v4[i] = ((r32 & 2) ? v8[2 * i + 1] : v8[2 * i]) + t;
    }
    float v2[2];
    #pragma unroll
    for (int i = 0; i < 2; ++i) {
        float t = (r32 & 4) ? v4[2 * i] : v4[2 * i + 1];
        t = __shfl_xor(t, 4, 64);
        v2[i] = ((r32 & 4) ? v4[2 * i + 1] : v4[2 * i]) + t;
    }
    float u;
    {
        float t = (r32 & 8) ? v2[0] : v2[1];
        t = __shfl_xor(t, 8, 64);
        u = ((r32 & 8) ? v2[1] : v2[0]) + t;
    }
    // u at lane l = S_{l&15} for rows of half g; one coalesced store
    if (r32 < 16) {
        const int rowr = (r32 & 3) + 8 * (r32 >> 2) + 4 * g;
        const int grow = nb + rowr;
        if (grow < N) out[b * N + grow] = u;
    }
    // wave total: butterfly of u counts each row twice -> x0.5
    float ts = u;
    #pragma unroll
    for (int off = 1; off < 64; off <<= 1) ts += __shfl_xor(ts, off, 64);
    if (lane == 0) wred[wt] = ts * 0.5f;
    __syncthreads();
    if (tid == 0)
        part[b * NRBF + blockIdx.x] = (wred[0] + wred[1]) + (wred[2] + wred[3]);
}

// ---------------- kernel 3: normalize (float4) ----------------
__global__ void k_norm(float* __restrict__ out, const float* __restrict__ part) {
    const int b = blockIdx.y;
    const int tid = threadIdx.x;
    const int f = blockIdx.x * 256 + tid;
    __shared__ float sdiv;
    if (tid < 64) {
        float v = part[b * NRBF + tid];
        if (tid + 64 < NRBF) v += part[b * NRBF + tid + 64];
        #pragma unroll
        for (int off = 32; off > 0; off >>= 1) v += __shfl_down(v, off, 64);
        if (tid == 0) sdiv = 1.f / (v + 1e-10f);
    }
    __syncthreads();
    if (f < N / 4) {
        float4* o4 = (float4*)(out + b * N);
        float4 v = o4[f];
        v.x *= sdiv; v.y *= sdiv; v.z *= sdiv; v.w *= sdiv;
        o4[f] = v;
    }
}

extern "C" void kernel_launch(void* const* d_in, const int* in_sizes, int n_in,
                              void* d_out, int out_size, void* d_ws, size_t ws_size,
                              hipStream_t stream) {
    const float* e   = (const float*)d_in[0];
    const float* rE  = (const float*)d_in[1];
    const float* sup = (const float*)d_in[2];
    const float* W1  = (const float*)d_in[3];
    const float* b1  = (const float*)d_in[4];
    const float* W2  = (const float*)d_in[5];
    const float* b2  = (const float*)d_in[6];
    float* out = (float*)d_out;

    char* ws = (char*)d_ws;
    float*  ow   = (float*)(ws + 0);
    float*  nm2  = (float*)(ws + 2048);
    ushort* tmh  = (ushort*)(ws + 4096);
    ushort* tml  = (ushort*)(ws + 69632);
    float*  part = (float*)(ws + 135168);

    hipLaunchKernelGGL(k_sel_mlp, dim3(B * 16), dim3(512), 0, stream,
                       e, rE, sup, W1, b1, W2, b2, ow, tmh, tml, nm2);
    hipLaunchKernelGGL(k_rbf, dim3(NRBF, B), dim3(256), 0, stream,
                       sup, tmh, tml, nm2, ow, out, part);
    hipLaunchKernelGGL(k_norm, dim3(10, B), dim3(256), 0, stream, out, part);
}

// Round 16
// 35.631 us; speedup vs baseline: 1.0258x; 1.0258x over previous
//
#include <hip/hip_runtime.h>
#include <hip/hip_bf16.h>

#define B 16
#define N 10000
#define D 64
#define R 64
#define H 512
#define K 32
#define NRBF 79                      // ceil(10000 / 128) rbf blocks per b
#define NBUCK 4096

typedef unsigned long long ull;
typedef short s16x8 __attribute__((ext_vector_type(8)));
typedef float f32x16 __attribute__((ext_vector_type(16)));

// ---------- ws layout (bytes) ----------
// lq   : B*K f32      @ 0        (2048)   -0.5*||mean||^2 + log(top_weight)
// tmh  : B*K*D bf16   @ 2048     (65536)  mean hi
// tml  : B*K*D bf16   @ 67584    (65536)  mean lo
// part : B*NRBF f32   @ 133120   (5056)

static __device__ __forceinline__ ushort f2bf_bits(float x) {
    __hip_bfloat16 h = __float2bfloat16(x);
    return *reinterpret_cast<ushort*>(&h);
}
static __device__ __forceinline__ float bf_hi_f(float x) {
    return __bfloat162float(__float2bfloat16(x));
}
// split 8 floats (two float4) into bf16 hi / lo fragments
static __device__ __forceinline__ void split8(const float4 a, const float4 b,
                                              s16x8& hi, s16x8& lo) {
    const float v[8] = {a.x, a.y, a.z, a.w, b.x, b.y, b.z, b.w};
    #pragma unroll
    for (int i = 0; i < 8; ++i) {
        const ushort h = f2bf_bits(v[i]);
        const float hf = __uint_as_float(((unsigned)h) << 16);
        hi[i] = (short)h;
        lo[i] = (short)f2bf_bits(v[i] - hf);
    }
}

// ------- kernel 1: redundant top-K select + MLP (16 blocks per b) -------
// Every block of batch b recomputes the SAME exact top-K via histogram select
// (deterministic: same input -> same histogram -> same threshold; slots are
// value-determined ranks with key = val_bits<<32 | ~idx, preserving jax's
// smaller-index tie-break). oidx never leaves LDS. Each block then runs the
// MLP for its 2 selected rows and emits mean (bf16 hi/lo) +
// lq = -0.5*||mean||^2 + log(top_weight)  (weight folded into the exp).
__global__ __launch_bounds__(512) void k_sel_mlp(
        const float* __restrict__ e, const float* __restrict__ rE,
        const float* __restrict__ sup, const float* __restrict__ W1,
        const float* __restrict__ b1, const float* __restrict__ W2,
        const float* __restrict__ b2,
        ushort* __restrict__ tmh, ushort* __restrict__ tml,
        float* __restrict__ lq) {
    const int b = blockIdx.x >> 4, pr = blockIdx.x & 15;
    const int tid = threadIdx.x;
    __shared__ unsigned hist[NBUCK];
    __shared__ ull cand[1024];
    __shared__ float rEs[R];
    __shared__ int oidxS[K];
    __shared__ float swS[2];
    __shared__ float sA[D], sB[D];
    __shared__ float hA[H], hB[H];
    __shared__ float partA[512], partB[512];
    __shared__ unsigned cnt;
    __shared__ int tsh;

    #pragma unroll
    for (int i = 0; i < NBUCK / 512; ++i) hist[tid + i * 512] = 0;
    if (tid == 0) cnt = 0;
    if (tid < R) rEs[tid] = rE[b * R + tid];
    __syncthreads();

    // ---- pass 1: histogram (2500 float4 = 10000 elems; 5 vec-loads/thread)
    const float4* e4 = (const float4*)(e + b * N);
    #pragma unroll
    for (int i = 0; i < 5; ++i) {
        const int fi = tid + i * 512;
        if (fi < 2500) {
            const float4 v4 = e4[fi];
            const float vv[4] = {v4.x, v4.y, v4.z, v4.w};
            #pragma unroll
            for (int j = 0; j < 4; ++j) {
                int bu = (int)(vv[j] * (float)NBUCK);
                bu = bu > NBUCK - 1 ? NBUCK - 1 : (bu < 0 ? 0 : bu);
                atomicAdd(&hist[bu], 1u);
            }
        }
    }
    __syncthreads();

    // wave 0: parallel suffix scan from the top, 64 buckets per step
    if (tid < 64) {
        unsigned acc = 0;
        for (int w = 0; w < NBUCK / 64; ++w) {
            const int j = NBUCK - 1 - (w * 64 + tid);
            unsigned p = hist[j];
            #pragma unroll
            for (int off = 1; off < 64; off <<= 1) {
                unsigned o = __shfl_up(p, off, 64);
                if (tid >= off) p += o;
            }
            const ull mask = __ballot(acc + p >= K);
            if (mask) {
                if (tid == 0) {
                    const int l0 = __ffsll((long long)mask) - 1;
                    tsh = NBUCK - 1 - (w * 64 + l0);
                }
                break;
            }
            acc += (unsigned)__shfl((int)p, 63, 64);
        }
    }
    __syncthreads();
    const int t = tsh;

    // ---- pass 2: re-read (L2-hot), collect candidates >= threshold
    #pragma unroll
    for (int i = 0; i < 5; ++i) {
        const int fi = tid + i * 512;
        if (fi < 2500) {
            const float4 v4 = e4[fi];
            const float vv[4] = {v4.x, v4.y, v4.z, v4.w};
            #pragma unroll
            for (int j = 0; j < 4; ++j) {
                int bu = (int)(vv[j] * (float)NBUCK);
                bu = bu > NBUCK - 1 ? NBUCK - 1 : (bu < 0 ? 0 : bu);
                if (bu >= t) {
                    const unsigned p = atomicAdd(&cnt, 1u);
                    if (p < 1024u)
                        cand[p] = ((ull)__float_as_uint(vv[j]) << 32) |
                                  (unsigned)(0xFFFFFFFFu - (unsigned)(fi * 4 + j));
                }
            }
        }
    }
    __syncthreads();

    const unsigned C = cnt < 1024u ? cnt : 1024u;
    for (unsigned i = tid; i < C; i += 512) {
        const ull mine = cand[i];
        int rank = 0;
        for (unsigned j = 0; j < C; ++j) rank += (cand[j] > mine);
        if (rank < K) {
            oidxS[rank] = (int)(0xFFFFFFFFu - (unsigned)(mine & 0xFFFFFFFFu));
            if ((rank >> 1) == pr)            // stash this block's 2 weights
                swS[rank & 1] = __uint_as_float((unsigned)(mine >> 32));
        }
    }
    __syncthreads();

    // ---- MLP on this block's 2 selected rows ----
    const int gk = b * K + pr * 2;
    const int id0 = oidxS[pr * 2], id1 = oidxS[pr * 2 + 1];
    if (tid < D) sA[tid] = sup[id0 * D + tid];
    else if (tid < 2 * D) sB[tid - D] = sup[id1 * D + (tid - D)];
    __syncthreads();

    {   // phase 1: one h-row per thread; rp inline (W1 cols 0..R, same row)
        const float4* w = (const float4*)(W1 + tid * (R + D));
        float rpv = b1[tid];
        #pragma unroll
        for (int i = 0; i < R / 4; ++i) {
            const float4 wv = w[i];
            rpv += wv.x * rEs[4 * i] + wv.y * rEs[4 * i + 1] +
                   wv.z * rEs[4 * i + 2] + wv.w * rEs[4 * i + 3];
        }
        float a0 = rpv, a1 = rpv;
        #pragma unroll
        for (int i = 0; i < D / 4; ++i) {
            const float4 wv = w[R / 4 + i];
            a0 += wv.x * sA[4 * i] + wv.y * sA[4 * i + 1] +
                  wv.z * sA[4 * i + 2] + wv.w * sA[4 * i + 3];
            a1 += wv.x * sB[4 * i] + wv.y * sB[4 * i + 1] +
                  wv.z * sB[4 * i + 2] + wv.w * sB[4 * i + 3];
        }
        hA[tid] = fmaxf(a0, 0.f);
        hB[tid] = fmaxf(a1, 0.f);
    }
    __syncthreads();

    {   // phase 2: d = tid&63, 8 chunks of 64 over H
        const int d = tid & 63, ch = tid >> 6;
        const float4* w2 = (const float4*)(W2 + d * H + ch * 64);
        float a0 = 0.f, a1 = 0.f;
        #pragma unroll
        for (int i = 0; i < 16; ++i) {
            const float4 wv = w2[i];
            const int hb = ch * 64 + 4 * i;
            a0 += wv.x * hA[hb] + wv.y * hA[hb + 1] + wv.z * hA[hb + 2] + wv.w * hA[hb + 3];
            a1 += wv.x * hB[hb] + wv.y * hB[hb + 1] + wv.z * hB[hb + 2] + wv.w * hB[hb + 3];
        }
        partA[tid] = a0;
        partB[tid] = a1;
    }
    __syncthreads();

    if (tid < 128) {            // wave 0 -> pair 0, wave 1 -> pair 1
        const int d = tid & 63, pw = tid >> 6;
        const float* part = pw == 0 ? partA : partB;
        float m = b2[d];
        #pragma unroll
        for (int c = 0; c < 8; ++c) m += part[c * 64 + d];
        const float hf = bf_hi_f(m);
        tmh[(gk + pw) * D + d] = f2bf_bits(m);
        tml[(gk + pw) * D + d] = f2bf_bits(m - hf);
        float sq = m * m;
        #pragma unroll
        for (int off = 32; off > 0; off >>= 1) sq += __shfl_down(sq, off, 64);
        if (d == 0) lq[gk + pw] = -0.5f * sq + __logf(swS[pw]);
    }
}

// ---------------- kernel 2: RBF via SWAPPED 32x32x16 split-bf16 MFMA --------
// C = tm x sup^T: A-frag = tm row k=lane&31, B-frag = sup row n=nb+(lane&31);
// both use d = s*16 + (lane>>5)*8 + j (identical lane->d map -> HW k-perm
// harmless). C/D: col=lane&31 = n (lane-local!), row r -> k=(r&3)+8*(r>>2)+4g.
// Epilogue: t_g = sum_r exp(ns2 + acc[r] + lq[k]) (ns2 lane-local from own
// sup loads; lq from a 128B LDS table), one shfl_xor(32) merges k-halves ->
// full sum; coalesced 32-lane store. ~8 cross-lane ops vs 55 in the unswapped
// form.
__global__ __launch_bounds__(256) void k_rbf(
        const float* __restrict__ sup,
        const ushort* __restrict__ tmh, const ushort* __restrict__ tml,
        const float* __restrict__ lq,
        float* __restrict__ out, float* __restrict__ part) {
    const int b = blockIdx.y;
    const int tid = threadIdx.x;
    const int lane = tid & 63;
    const int wt = tid >> 6;
    const int g = lane >> 5;                 // d-half / k-half selector
    const int r32 = lane & 31;
    const int nb = blockIdx.x * 128 + wt * 32;
    __shared__ float lqS[K];
    __shared__ float wred[4];

    if (tid < K) lqS[tid] = lq[b * K + tid];

    const int n = nb + r32;
    const int nc = n < N ? n : N - 1;

    // B operand: sup row n (lane's output col), d-half g; split + local norm
    s16x8 sbh[4], sbl[4];
    float s2o = 0.f;
    const float4* sp = (const float4*)(sup + nc * D);
    #pragma unroll
    for (int s = 0; s < 4; ++s) {
        const float4 u0 = sp[s * 4 + g * 2];
        const float4 u1 = sp[s * 4 + g * 2 + 1];
        s2o += u0.x * u0.x + u0.y * u0.y + u0.z * u0.z + u0.w * u0.w
             + u1.x * u1.x + u1.y * u1.y + u1.z * u1.z + u1.w * u1.w;
        split8(u0, u1, sbh[s], sbl[s]);
    }
    const float ns2 = -0.5f * (s2o + __shfl_xor(s2o, 32, 64)); // own-n norm

    // A operand: tm row k = r32, d-half g (bf16 hi/lo)
    const ushort* ph = tmh + (b * K + r32) * D;
    const ushort* pl = tml + (b * K + r32) * D;
    s16x8 ath[4], atl[4];
    #pragma unroll
    for (int s = 0; s < 4; ++s) {
        ath[s] = *(const s16x8*)(ph + s * 16 + g * 8);
        atl[s] = *(const s16x8*)(pl + s * 16 + g * 8);
    }

    f32x16 acc = {0.f, 0.f, 0.f, 0.f, 0.f, 0.f, 0.f, 0.f,
                  0.f, 0.f, 0.f, 0.f, 0.f, 0.f, 0.f, 0.f};
    #pragma unroll
    for (int s = 0; s < 4; ++s) {            // mh*sh + mh*sl + ml*sh
        acc = __builtin_amdgcn_mfma_f32_32x32x16_bf16(ath[s], sbh[s], acc, 0, 0, 0);
        acc = __builtin_amdgcn_mfma_f32_32x32x16_bf16(ath[s], sbl[s], acc, 0, 0, 0);
        acc = __builtin_amdgcn_mfma_f32_32x32x16_bf16(atl[s], sbh[s], acc, 0, 0, 0);
    }

    __syncthreads();                          // lqS visible

    float tg = 0.f;
    #pragma unroll
    for (int r = 0; r < 16; ++r) {
        const int kk = (r & 3) + 8 * (r >> 2) + 4 * g;
        tg += __expf(ns2 + acc[r] + lqS[kk]);
    }
    float t = tg + __shfl_xor(tg, 32, 64);    // merge the two k-halves
    if (n >= N) t = 0.f;
    if (g == 0 && n < N) out[b * N + n] = t;  // coalesced 32-lane store

    // block partial: butterfly over the 32-lane group (halves identical)
    float ts = t;
    #pragma unroll
    for (int off = 1; off < 32; off <<= 1) ts += __shfl_xor(ts, off, 64);
    if (lane == 0) wred[wt] = ts;
    __syncthreads();
    if (tid == 0)
        part[b * NRBF + blockIdx.x] = (wred[0] + wred[1]) + (wred[2] + wred[3]);
}

// ---------------- kernel 3: normalize (float4) ----------------
__global__ void k_norm(float* __restrict__ out, const float* __restrict__ part) {
    const int b = blockIdx.y;
    const int tid = threadIdx.x;
    const int f = blockIdx.x * 256 + tid;
    __shared__ float sdiv;
    if (tid < 64) {
        float v = part[b * NRBF + tid];
        if (tid + 64 < NRBF) v += part[b * NRBF + tid + 64];
        #pragma unroll
        for (int off = 32; off > 0; off >>= 1) v += __shfl_down(v, off, 64);
        if (tid == 0) sdiv = 1.f / (v + 1e-10f);
    }
    __syncthreads();
    if (f < N / 4) {
        float4* o4 = (float4*)(out + b * N);
        float4 v = o4[f];
        v.x *= sdiv; v.y *= sdiv; v.z *= sdiv; v.w *= sdiv;
        o4[f] = v;
    }
}

extern "C" void kernel_launch(void* const* d_in, const int* in_sizes, int n_in,
                              void* d_out, int out_size, void* d_ws, size_t ws_size,
                              hipStream_t stream) {
    const float* e   = (const float*)d_in[0];
    const float* rE  = (const float*)d_in[1];
    const float* sup = (const float*)d_in[2];
    const float* W1  = (const float*)d_in[3];
    const float* b1  = (const float*)d_in[4];
    const float* W2  = (const float*)d_in[5];
    const float* b2  = (const float*)d_in[6];
    float* out = (float*)d_out;

    char* ws = (char*)d_ws;
    float*  lq   = (float*)(ws + 0);
    ushort* tmh  = (ushort*)(ws + 2048);
    ushort* tml  = (ushort*)(ws + 67584);
    float*  part = (float*)(ws + 133120);

    hipLaunchKernelGGL(k_sel_mlp, dim3(B * 16), dim3(512), 0, stream,
                       e, rE, sup, W1, b1, W2, b2, tmh, tml, lq);
    hipLaunchKernelGGL(k_rbf, dim3(NRBF, B), dim3(256), 0, stream,
                       sup, tmh, tml, lq, out, part);
    hipLaunchKernelGGL(k_norm, dim3(10, B), dim3(256), 0, stream, out, part);
}

// Round 18
// 35.561 us; speedup vs baseline: 1.0278x; 1.0019x over previous
//
#include <hip/hip_runtime.h>
#include <hip/hip_bf16.h>

#define B 16
#define N 10000
#define D 64
#define R 64
#define H 512
#define K 32
#define NRBF 79                      // ceil(10000 / 128) rbf blocks per b
#define NBUCK 4096

typedef unsigned long long ull;
typedef short s16x8 __attribute__((ext_vector_type(8)));
typedef float f32x16 __attribute__((ext_vector_type(16)));

// ---------- ws layout (bytes) ----------
// lq   : B*K f32      @ 0        (2048)   -0.5*||mean||^2 + log(top_weight)
// tmh  : B*K*D bf16   @ 2048     (65536)  mean hi
// tml  : B*K*D bf16   @ 67584    (65536)  mean lo
// part : B*NRBF f32   @ 133120   (5056)

static __device__ __forceinline__ ushort f2bf_bits(float x) {
    __hip_bfloat16 h = __float2bfloat16(x);
    return *reinterpret_cast<ushort*>(&h);
}
static __device__ __forceinline__ float bf_hi_f(float x) {
    return __bfloat162float(__float2bfloat16(x));
}
// split 8 floats (two float4) into bf16 hi / lo fragments
static __device__ __forceinline__ void split8(const float4 a, const float4 b,
                                              s16x8& hi, s16x8& lo) {
    const float v[8] = {a.x, a.y, a.z, a.w, b.x, b.y, b.z, b.w};
    #pragma unroll
    for (int i = 0; i < 8; ++i) {
        const ushort h = f2bf_bits(v[i]);
        const float hf = __uint_as_float(((unsigned)h) << 16);
        hi[i] = (short)h;
        lo[i] = (short)f2bf_bits(v[i] - hf);
    }
}

// ------- kernel 1: redundant top-K select + MLP (16 blocks per b) -------
// Every block of batch b recomputes the SAME exact top-K via histogram select
// (deterministic: same input -> same histogram -> same threshold; slots are
// value-determined ranks with key = val_bits<<32 | ~idx, preserving jax's
// smaller-index tie-break). oidx never leaves LDS. Each block then runs the
// MLP for its 2 selected rows and emits mean (bf16 hi/lo) +
// lq = -0.5*||mean||^2 + log(top_weight)  (weight folded into the exp).
__global__ __launch_bounds__(512) void k_sel_mlp(
        const float* __restrict__ e, const float* __restrict__ rE,
        const float* __restrict__ sup, const float* __restrict__ W1,
        const float* __restrict__ b1, const float* __restrict__ W2,
        const float* __restrict__ b2,
        ushort* __restrict__ tmh, ushort* __restrict__ tml,
        float* __restrict__ lq) {
    const int b = blockIdx.x >> 4, pr = blockIdx.x & 15;
    const int tid = threadIdx.x;
    __shared__ unsigned hist[NBUCK];
    __shared__ ull cand[1024];
    __shared__ float rEs[R];
    __shared__ int oidxS[K];
    __shared__ float swS[2];
    __shared__ float sA[D], sB[D];
    __shared__ float hA[H], hB[H];
    __shared__ float partA[512], partB[512];
    __shared__ unsigned cnt;
    __shared__ int tsh;

    #pragma unroll
    for (int i = 0; i < NBUCK / 512; ++i) hist[tid + i * 512] = 0;
    if (tid == 0) cnt = 0;
    if (tid < R) rEs[tid] = rE[b * R + tid];
    __syncthreads();

    // ---- pass 1: histogram (2500 float4 = 10000 elems; 5 vec-loads/thread)
    const float4* e4 = (const float4*)(e + b * N);
    #pragma unroll
    for (int i = 0; i < 5; ++i) {
        const int fi = tid + i * 512;
        if (fi < 2500) {
            const float4 v4 = e4[fi];
            const float vv[4] = {v4.x, v4.y, v4.z, v4.w};
            #pragma unroll
            for (int j = 0; j < 4; ++j) {
                int bu = (int)(vv[j] * (float)NBUCK);
                bu = bu > NBUCK - 1 ? NBUCK - 1 : (bu < 0 ? 0 : bu);
                atomicAdd(&hist[bu], 1u);
            }
        }
    }
    __syncthreads();

    // wave 0: parallel suffix scan from the top, 64 buckets per step
    if (tid < 64) {
        unsigned acc = 0;
        for (int w = 0; w < NBUCK / 64; ++w) {
            const int j = NBUCK - 1 - (w * 64 + tid);
            unsigned p = hist[j];
            #pragma unroll
            for (int off = 1; off < 64; off <<= 1) {
                unsigned o = __shfl_up(p, off, 64);
                if (tid >= off) p += o;
            }
            const ull mask = __ballot(acc + p >= K);
            if (mask) {
                if (tid == 0) {
                    const int l0 = __ffsll((long long)mask) - 1;
                    tsh = NBUCK - 1 - (w * 64 + l0);
                }
                break;
            }
            acc += (unsigned)__shfl((int)p, 63, 64);
        }
    }
    __syncthreads();
    const int t = tsh;

    // ---- pass 2: re-read (L2-hot), collect candidates >= threshold
    #pragma unroll
    for (int i = 0; i < 5; ++i) {
        const int fi = tid + i * 512;
        if (fi < 2500) {
            const float4 v4 = e4[fi];
            const float vv[4] = {v4.x, v4.y, v4.z, v4.w};
            #pragma unroll
            for (int j = 0; j < 4; ++j) {
                int bu = (int)(vv[j] * (float)NBUCK);
                bu = bu > NBUCK - 1 ? NBUCK - 1 : (bu < 0 ? 0 : bu);
                if (bu >= t) {
                    const unsigned p = atomicAdd(&cnt, 1u);
                    if (p < 1024u)
                        cand[p] = ((ull)__float_as_uint(vv[j]) << 32) |
                                  (unsigned)(0xFFFFFFFFu - (unsigned)(fi * 4 + j));
                }
            }
        }
    }
    __syncthreads();

    const unsigned C = cnt < 1024u ? cnt : 1024u;
    for (unsigned i = tid; i < C; i += 512) {
        const ull mine = cand[i];
        int rank = 0;
        for (unsigned j = 0; j < C; ++j) rank += (cand[j] > mine);
        if (rank < K) {
            oidxS[rank] = (int)(0xFFFFFFFFu - (unsigned)(mine & 0xFFFFFFFFu));
            if ((rank >> 1) == pr)            // stash this block's 2 weights
                swS[rank & 1] = __uint_as_float((unsigned)(mine >> 32));
        }
    }
    __syncthreads();

    // ---- MLP on this block's 2 selected rows ----
    const int gk = b * K + pr * 2;
    const int id0 = oidxS[pr * 2], id1 = oidxS[pr * 2 + 1];
    if (tid < D) sA[tid] = sup[id0 * D + tid];
    else if (tid < 2 * D) sB[tid - D] = sup[id1 * D + (tid - D)];
    __syncthreads();

    {   // phase 1: one h-row per thread; rp inline (W1 cols 0..R, same row)
        const float4* w = (const float4*)(W1 + tid * (R + D));
        float rpv = b1[tid];
        #pragma unroll
        for (int i = 0; i < R / 4; ++i) {
            const float4 wv = w[i];
            rpv += wv.x * rEs[4 * i] + wv.y * rEs[4 * i + 1] +
                   wv.z * rEs[4 * i + 2] + wv.w * rEs[4 * i + 3];
        }
        float a0 = rpv, a1 = rpv;
        #pragma unroll
        for (int i = 0; i < D / 4; ++i) {
            const float4 wv = w[R / 4 + i];
            a0 += wv.x * sA[4 * i] + wv.y * sA[4 * i + 1] +
                  wv.z * sA[4 * i + 2] + wv.w * sA[4 * i + 3];
            a1 += wv.x * sB[4 * i] + wv.y * sB[4 * i + 1] +
                  wv.z * sB[4 * i + 2] + wv.w * sB[4 * i + 3];
        }
        hA[tid] = fmaxf(a0, 0.f);
        hB[tid] = fmaxf(a1, 0.f);
    }
    __syncthreads();

    {   // phase 2: d = tid&63, 8 chunks of 64 over H
        const int d = tid & 63, ch = tid >> 6;
        const float4* w2 = (const float4*)(W2 + d * H + ch * 64);
        float a0 = 0.f, a1 = 0.f;
        #pragma unroll
        for (int i = 0; i < 16; ++i) {
            const float4 wv = w2[i];
            const int hb = ch * 64 + 4 * i;
            a0 += wv.x * hA[hb] + wv.y * hA[hb + 1] + wv.z * hA[hb + 2] + wv.w * hA[hb + 3];
            a1 += wv.x * hB[hb] + wv.y * hB[hb + 1] + wv.z * hB[hb + 2] + wv.w * hB[hb + 3];
        }
        partA[tid] = a0;
        partB[tid] = a1;
    }
    __syncthreads();

    if (tid < 128) {            // wave 0 -> pair 0, wave 1 -> pair 1
        const int d = tid & 63, pw = tid >> 6;
        const float* part = pw == 0 ? partA : partB;
        float m = b2[d];
        #pragma unroll
        for (int c = 0; c < 8; ++c) m += part[c * 64 + d];
        const float hf = bf_hi_f(m);
        tmh[(gk + pw) * D + d] = f2bf_bits(m);
        tml[(gk + pw) * D + d] = f2bf_bits(m - hf);
        float sq = m * m;
        #pragma unroll
        for (int off = 32; off > 0; off >>= 1) sq += __shfl_down(sq, off, 64);
        if (d == 0) lq[gk + pw] = -0.5f * sq + __logf(swS[pw]);
    }
}

// ---------------- kernel 2: RBF via SWAPPED 32x32x16 split-bf16 MFMA --------
// C = tm x sup^T: A-frag = tm row k=lane&31, B-frag = sup row n=nb+(lane&31);
// both use d = s*16 + (lane>>5)*8 + j (identical lane->d map -> HW k-perm
// harmless). C/D: col=lane&31 = n (lane-local!), row r -> k=(r&3)+8*(r>>2)+4g.
// Epilogue: t_g = sum_r exp(ns2 + acc[r] + lq[k]) (ns2 lane-local from own
// sup loads; lq from a 128B LDS table), one shfl_xor(32) merges k-halves ->
// full sum; coalesced 32-lane store.
__global__ __launch_bounds__(256) void k_rbf(
        const float* __restrict__ sup,
        const ushort* __restrict__ tmh, const ushort* __restrict__ tml,
        const float* __restrict__ lq,
        float* __restrict__ out, float* __restrict__ part) {
    const int b = blockIdx.y;
    const int tid = threadIdx.x;
    const int lane = tid & 63;
    const int wt = tid >> 6;
    const int g = lane >> 5;                 // d-half / k-half selector
    const int r32 = lane & 31;
    const int nb = blockIdx.x * 128 + wt * 32;
    __shared__ float lqS[K];
    __shared__ float wred[4];

    if (tid < K) lqS[tid] = lq[b * K + tid];

    const int n = nb + r32;
    const int nc = n < N ? n : N - 1;

    // B operand: sup row n (lane's output col), d-half g; split + local norm
    s16x8 sbh[4], sbl[4];
    float s2o = 0.f;
    const float4* sp = (const float4*)(sup + nc * D);
    #pragma unroll
    for (int s = 0; s < 4; ++s) {
        const float4 u0 = sp[s * 4 + g * 2];
        const float4 u1 = sp[s * 4 + g * 2 + 1];
        s2o += u0.x * u0.x + u0.y * u0.y + u0.z * u0.z + u0.w * u0.w
             + u1.x * u1.x + u1.y * u1.y + u1.z * u1.z + u1.w * u1.w;
        split8(u0, u1, sbh[s], sbl[s]);
    }
    const float ns2 = -0.5f * (s2o + __shfl_xor(s2o, 32, 64)); // own-n norm

    // A operand: tm row k = r32, d-half g (bf16 hi/lo)
    const ushort* ph = tmh + (b * K + r32) * D;
    const ushort* pl = tml + (b * K + r32) * D;
    s16x8 ath[4], atl[4];
    #pragma unroll
    for (int s = 0; s < 4; ++s) {
        ath[s] = *(const s16x8*)(ph + s * 16 + g * 8);
        atl[s] = *(const s16x8*)(pl + s * 16 + g * 8);
    }

    f32x16 acc = {0.f, 0.f, 0.f, 0.f, 0.f, 0.f, 0.f, 0.f,
                  0.f, 0.f, 0.f, 0.f, 0.f, 0.f, 0.f, 0.f};
    #pragma unroll
    for (int s = 0; s < 4; ++s) {            // mh*sh + mh*sl + ml*sh
        acc = __builtin_amdgcn_mfma_f32_32x32x16_bf16(ath[s], sbh[s], acc, 0, 0, 0);
        acc = __builtin_amdgcn_mfma_f32_32x32x16_bf16(ath[s], sbl[s], acc, 0, 0, 0);
        acc = __builtin_amdgcn_mfma_f32_32x32x16_bf16(atl[s], sbh[s], acc, 0, 0, 0);
    }

    __syncthreads();                          // lqS visible

    float tg = 0.f;
    #pragma unroll
    for (int r = 0; r < 16; ++r) {
        const int kk = (r & 3) + 8 * (r >> 2) + 4 * g;
        tg += __expf(ns2 + acc[r] + lqS[kk]);
    }
    float t = tg + __shfl_xor(tg, 32, 64);    // merge the two k-halves
    if (n >= N) t = 0.f;
    if (g == 0 && n < N) out[b * N + n] = t;  // coalesced 32-lane store

    // block partial: butterfly over the 32-lane group (halves identical)
    float ts = t;
    #pragma unroll
    for (int off = 1; off < 32; off <<= 1) ts += __shfl_xor(ts, off, 64);
    if (lane == 0) wred[wt] = ts;
    __syncthreads();
    if (tid == 0)
        part[b * NRBF + blockIdx.x] = (wred[0] + wred[1]) + (wred[2] + wred[3]);
}

// ---------------- kernel 3: normalize (float4) ----------------
__global__ void k_norm(float* __restrict__ out, const float* __restrict__ part) {
    const int b = blockIdx.y;
    const int tid = threadIdx.x;
    const int f = blockIdx.x * 256 + tid;
    __shared__ float sdiv;
    if (tid < 64) {
        float v = part[b * NRBF + tid];
        if (tid + 64 < NRBF) v += part[b * NRBF + tid + 64];
        #pragma unroll
        for (int off = 32; off > 0; off >>= 1) v += __shfl_down(v, off, 64);
        if (tid == 0) sdiv = 1.f / (v + 1e-10f);
    }
    __syncthreads();
    if (f < N / 4) {
        float4* o4 = (float4*)(out + b * N);
        float4 v = o4[f];
        v.x *= sdiv; v.y *= sdiv; v.z *= sdiv; v.w *= sdiv;
        o4[f] = v;
    }
}

extern "C" void kernel_launch(void* const* d_in, const int* in_sizes, int n_in,
                              void* d_out, int out_size, void* d_ws, size_t ws_size,
                              hipStream_t stream) {
    const float* e   = (const float*)d_in[0];
    const float* rE  = (const float*)d_in[1];
    const float* sup = (const float*)d_in[2];
    const float* W1  = (const float*)d_in[3];
    const float* b1  = (const float*)d_in[4];
    const float* W2  = (const float*)d_in[5];
    const float* b2  = (const float*)d_in[6];
    float* out = (float*)d_out;

    char* ws = (char*)d_ws;
    float*  lq   = (float*)(ws + 0);
    ushort* tmh  = (ushort*)(ws + 2048);
    ushort* tml  = (ushort*)(ws + 67584);
    float*  part = (float*)(ws + 133120);

    hipLaunchKernelGGL(k_sel_mlp, dim3(B * 16), dim3(512), 0, stream,
                       e, rE, sup, W1, b1, W2, b2, tmh, tml, lq);
    hipLaunchKernelGGL(k_rbf, dim3(NRBF, B), dim3(256), 0, stream,
                       sup, tmh, tml, lq, out, part);
    hipLaunchKernelGGL(k_norm, dim3(10, B), dim3(256), 0, stream, out, part);
}